// Round 2
// baseline (443.755 us; speedup 1.0000x reference)
//
#include <hip/hip_runtime.h>

#define NROWS 32768
#define DDIM  128
#define KCODES 1024
#define DECAY 0.99f
#define OMD   0.01f
#define EPS   1e-5f

#define TM 64
#define XS_STRIDE 132   // 128 + 4 pad: float4-aligned, 2-way bank alias (free per m136)
#define ES_STRIDE 36    // 32 + 4 pad

// ws layout (floats): [counts 1024][embed_sum 131072][en2h 1024][inv 1024]
#define WS_COUNTS 0
#define WS_ESUM   1024
#define WS_EN2H   (1024 + 131072)
#define WS_INV    (1024 + 131072 + 1024)

// ---- K0: half squared norms of codebook rows; one wave per code ----
__global__ void norms_kernel(const float* __restrict__ embed, float* __restrict__ en2h) {
  int w = threadIdx.x >> 6;
  int lane = threadIdx.x & 63;
  int k = blockIdx.x * 4 + w;
  const float2* p = (const float2*)(embed + k * DDIM);
  float2 v = p[lane];
  float s = v.x * v.x + v.y * v.y;
  #pragma unroll
  for (int off = 32; off > 0; off >>= 1) s += __shfl_down(s, off, 64);
  if (lane == 0) en2h[k] = 0.5f * s;
}

// ---- K1: distance argmax + quantize + scatter (counts, embed_sum) ----
__global__ __launch_bounds__(256) void vq_main(
    const float* __restrict__ x, const float* __restrict__ embed,
    const float* __restrict__ en2h,
    float* __restrict__ counts, float* __restrict__ esum,
    float* __restrict__ out_q, float* __restrict__ out_ind) {
  __shared__ float xs[TM * XS_STRIDE];        // 33792 B
  __shared__ float es[128 * ES_STRIDE];       // 18432 B
  __shared__ float redv[TM * 16];
  __shared__ int   redi[TM * 16];
  __shared__ int   idxs[TM];

  const int tid = threadIdx.x;
  const int tx = tid & 15;          // code group
  const int ty = tid >> 4;          // row group
  const int row0 = blockIdx.x * TM;

  // stage x tile once (rows row0..row0+63, full D)
  #pragma unroll
  for (int it = 0; it < 8; ++it) {
    int idx = tid + 256 * it;
    int row = idx >> 5, d4 = idx & 31;
    *(float4*)(xs + row * XS_STRIDE + d4 * 4) =
        *(const float4*)(x + (row0 + row) * DDIM + d4 * 4);
  }

  float bestv[4]; int besti[4];
  #pragma unroll
  for (int i = 0; i < 4; ++i) { bestv[i] = -3.4e38f; besti[i] = 0; }

  for (int cc = 0; cc < KCODES; cc += 128) {
    float acc[4][8];
    #pragma unroll
    for (int i = 0; i < 4; ++i)
      #pragma unroll
      for (int j = 0; j < 8; ++j) acc[i][j] = 0.f;

    for (int dd = 0; dd < DDIM; dd += 32) {
      __syncthreads();  // prior readers done with es (also orders xs staging stores)
      #pragma unroll
      for (int it = 0; it < 4; ++it) {
        int idx = tid + 256 * it;
        int c = idx >> 3, d4 = idx & 7;
        *(float4*)(es + c * ES_STRIDE + d4 * 4) =
            *(const float4*)(embed + (cc + c) * DDIM + dd + d4 * 4);
      }
      __syncthreads();
      #pragma unroll
      for (int d4 = 0; d4 < 8; ++d4) {
        float4 xv[4], ev[8];
        #pragma unroll
        for (int i = 0; i < 4; ++i)
          xv[i] = *(const float4*)(xs + (ty * 4 + i) * XS_STRIDE + dd + d4 * 4);
        #pragma unroll
        for (int j = 0; j < 8; ++j)
          ev[j] = *(const float4*)(es + (j * 16 + tx) * ES_STRIDE + d4 * 4);
        #pragma unroll
        for (int i = 0; i < 4; ++i)
          #pragma unroll
          for (int j = 0; j < 8; ++j)
            acc[i][j] += xv[i].x * ev[j].x + xv[i].y * ev[j].y +
                         xv[i].z * ev[j].z + xv[i].w * ev[j].w;
      }
    }
    // fold scores into running best (score = x.e - 0.5*|e|^2; argmax-equivalent to ref)
    #pragma unroll
    for (int j = 0; j < 8; ++j) {
      int c = cc + j * 16 + tx;
      float nh = en2h[c];
      #pragma unroll
      for (int i = 0; i < 4; ++i) {
        float s = acc[i][j] - nh;
        if (s > bestv[i]) { bestv[i] = s; besti[i] = c; }  // strict >: keeps first max
      }
    }
  }

  __syncthreads();
  #pragma unroll
  for (int i = 0; i < 4; ++i) {
    redv[(ty * 4 + i) * 16 + tx] = bestv[i];
    redi[(ty * 4 + i) * 16 + tx] = besti[i];
  }
  __syncthreads();
  if (tid < TM) {
    float bv = redv[tid * 16]; int bi = redi[tid * 16];
    #pragma unroll
    for (int t = 1; t < 16; ++t) {
      float v = redv[tid * 16 + t]; int ix = redi[tid * 16 + t];
      if (v > bv || (v == bv && ix < bi)) { bv = v; bi = ix; }  // first-max tie rule
    }
    idxs[tid] = bi;
    out_ind[row0 + tid] = (float)bi;
    atomicAdd(counts + bi, 1.0f);
  }
  __syncthreads();

  // quantize gather-write (fp32, exact) + embed_sum scatter (fp32 atomics)
  #pragma unroll
  for (int it = 0; it < 8; ++it) {
    int idx = tid + 256 * it;
    int row = idx >> 5, d4 = idx & 31;
    int code = idxs[row];
    float4 e = *(const float4*)(embed + code * DDIM + d4 * 4);
    *(float4*)(out_q + (row0 + row) * DDIM + d4 * 4) = e;
    float4 xv = *(const float4*)(xs + row * XS_STRIDE + d4 * 4);
    int eb = code * DDIM + d4 * 4;
    atomicAdd(esum + eb + 0, xv.x);
    atomicAdd(esum + eb + 1, xv.y);
    atomicAdd(esum + eb + 2, xv.z);
    atomicAdd(esum + eb + 3, xv.w);
  }
}

// ---- K2: new_cluster_size, total, inverse smoothed ----
__global__ void fin1(const float* __restrict__ counts, const float* __restrict__ cs,
                     float* __restrict__ out_ncs, float* __restrict__ inv) {
  __shared__ float wsum[16];
  int tid = threadIdx.x;
  int lane = tid & 63, w = tid >> 6;
  float ncs = cs[tid] * DECAY + OMD * counts[tid];
  out_ncs[tid] = ncs;
  float s = ncs;
  #pragma unroll
  for (int off = 32; off > 0; off >>= 1) s += __shfl_down(s, off, 64);
  if (lane == 0) wsum[w] = s;
  __syncthreads();
  if (tid == 0) {
    float t = 0.f;
    #pragma unroll
    for (int i = 0; i < 16; ++i) t += wsum[i];
    wsum[0] = t;
  }
  __syncthreads();
  float total = wsum[0];
  // new_embed = nea / smoothed, smoothed = (ncs+eps)/(total+K*eps)*total
  inv[tid] = (total + (float)KCODES * EPS) / ((ncs + EPS) * total);
}

// ---- K3: new_embed_avg + new_embed, elementwise ----
__global__ void fin2(const float* __restrict__ ea, const float* __restrict__ esum,
                     const float* __restrict__ inv,
                     float* __restrict__ out_nea, float* __restrict__ out_ne) {
  int gid = blockIdx.x * 256 + threadIdx.x;  // 0..32767, 4 elems each
  int base = gid * 4;
  int k = base >> 7;
  float4 a = *(const float4*)(ea + base);
  float4 s = *(const float4*)(esum + base);
  float iv = inv[k];
  float4 nea;
  nea.x = a.x * DECAY + OMD * s.x; nea.y = a.y * DECAY + OMD * s.y;
  nea.z = a.z * DECAY + OMD * s.z; nea.w = a.w * DECAY + OMD * s.w;
  *(float4*)(out_nea + base) = nea;
  float4 ne;
  ne.x = nea.x * iv; ne.y = nea.y * iv; ne.z = nea.z * iv; ne.w = nea.w * iv;
  *(float4*)(out_ne + base) = ne;
}

extern "C" void kernel_launch(void* const* d_in, const int* in_sizes, int n_in,
                              void* d_out, int out_size, void* d_ws, size_t ws_size,
                              hipStream_t stream) {
  const float* x     = (const float*)d_in[0];
  const float* embed = (const float*)d_in[1];
  const float* cs    = (const float*)d_in[2];
  const float* ea    = (const float*)d_in[3];

  float* out     = (float*)d_out;
  float* out_q   = out;                       // 4194304
  float* out_ind = out_q + 4194304;           // 32768
  float* out_ncs = out_ind + 32768;           // 1024
  float* out_nea = out_ncs + 1024;            // 131072
  float* out_ne  = out_nea + 131072;          // 131072

  float* ws     = (float*)d_ws;
  float* counts = ws + WS_COUNTS;
  float* esum   = ws + WS_ESUM;
  float* en2h   = ws + WS_EN2H;
  float* inv    = ws + WS_INV;

  hipMemsetAsync(ws, 0, (size_t)(1024 + 131072) * sizeof(float), stream);
  norms_kernel<<<KCODES / 4, 256, 0, stream>>>(embed, en2h);
  vq_main<<<NROWS / TM, 256, 0, stream>>>(x, embed, en2h, counts, esum, out_q, out_ind);
  fin1<<<1, 1024, 0, stream>>>(counts, cs, out_ncs, inv);
  fin2<<<131072 / 1024, 256, 0, stream>>>(ea, esum, inv, out_nea, out_ne);
}